// Round 1
// baseline (196.163 us; speedup 1.0000x reference)
//
#include <hip/hip_runtime.h>

#define INV_2PI 0.15915494309189535f

// v_sin_f32 takes REVOLUTIONS: computes sin(2*pi*x) directly, no range
// reduction needed (all args in ~[0,1]). volatile pins the relative order
// of the sins so batches stream through the trans pipe back-to-back.
__device__ __forceinline__ float vsin_pinned(float x) {
    float r;
    asm volatile("v_sin_f32 %0, %1" : "=v"(r) : "v"(x));
    return r;
}

// Batched diff_round: N independent sins issue back-to-back through the
// trans pipe, then N fmas whose operands are long-ready.
template <int N>
__device__ __forceinline__ void dround_batch(float* c) {
    float s[N];
#pragma unroll
    for (int i = 0; i < N; ++i) s[i] = vsin_pinned(c[i]);
#pragma unroll
    for (int i = 0; i < N; ++i) c[i] = __builtin_fmaf(-INV_2PI, s[i], c[i]);
}

// Tail of filter_mask_of_interest once hdr(mask channels) is in c[16]:
// eq-combine against (hb, vb), hdr(eq), then the differentiable_and tree.
// m[4] = per-pixel mask weight for this lane's 4 pixels.
__device__ __forceinline__ void filter_tail(float* c, const float* hb,
                                            const float* vb, float* m) {
#pragma unroll
    for (int i = 0; i < 16; ++i) {
        float om = 1.0f - c[i];
        c[i] = __builtin_fmaf(c[i], hb[i & 3], om * vb[i & 3]);
    }
    dround_batch<16>(c); dround_batch<16>(c); dround_batch<16>(c);
    dround_batch<16>(c);
    float p[8];
#pragma unroll
    for (int j = 0; j < 4; ++j) {
        p[2 * j]     = c[4 * j]     * c[4 * j + 1];
        p[2 * j + 1] = c[4 * j + 2] * c[4 * j + 3];
    }
    dround_batch<8>(p);
#pragma unroll
    for (int j = 0; j < 4; ++j) m[j] = p[2 * j] * p[2 * j + 1];
}

// One wave (64 lanes) per AREA; the wave computes BOTH mask variants:
// img/id loaded once, hb computed once, mask_alt loads in flight under
// variant-0's ~1800 cycles of sin work. Lane owns pixels {lane+64k} so
// every load/store instruction is contiguous across the wave
// (mask: 16B/lane = 1KB/instr; img/out: 4B/lane = 256B/instr).
__global__ __launch_bounds__(256) void De_conv_areas_kernel(
    const float* __restrict__ img,       // [A,256,1] f32
    const float* __restrict__ mask,      // [A,256,4] f32
    const float* __restrict__ mask_alt,  // [A,256,4] f32
    const float* __restrict__ mask_id,   // [A,4]     f32
    float* __restrict__ out,             // [A,256]   f32  (output 0)
    float* __restrict__ out_alt,         // [A,256]   f32  (output 1)
    int n_areas)
{
    const int lane = threadIdx.x & 63;
    int area = blockIdx.x * (blockDim.x >> 6) + (threadIdx.x >> 6);
    if (area >= n_areas) return;
    area = __builtin_amdgcn_readfirstlane(area);   // wave-uniform -> SGPR bases

    const size_t base = (size_t)area * 256;

    const float4* mp = (const float4*)mask     + base + lane;
    const float4* ap = (const float4*)mask_alt + base + lane;
    const float*  ip = img + base + lane;

    // Issue ALL VMEM up front; alt + img stay in flight under variant-0 compute.
    float4 q0 = mp[0], q1 = mp[64], q2 = mp[128], q3 = mp[192];
    float4 a0 = ap[0], a1 = ap[64], a2 = ap[128], a3 = ap[192];
    float  i0 = ip[0], i1 = ip[64], i2 = ip[128], i3 = ip[192];
    float4 idv = *(const float4*)(mask_id + (size_t)area * 4);  // uniform: s_load

    // Merged first hdr stage: hb (4 id channels) + variant-0 mask (16
    // channels) as one 20-wide sin stream — better trans packing than a
    // separate 4-wide hb chain.
    float c0[20] = { idv.x, idv.y, idv.z, idv.w,
                     q0.x, q0.y, q0.z, q0.w,  q1.x, q1.y, q1.z, q1.w,
                     q2.x, q2.y, q2.z, q2.w,  q3.x, q3.y, q3.z, q3.w };
    dround_batch<20>(c0); dround_batch<20>(c0); dround_batch<20>(c0);

    float hb[4] = { c0[0], c0[1], c0[2], c0[3] };
    float vb[4];
#pragma unroll
    for (int k = 0; k < 4; ++k) vb[k] = 1.0f - hb[k];

    float m0[4];
    filter_tail(c0 + 4, hb, vb, m0);

    // Variant 1: regs a0..a3 landed long ago.
    float c1[16] = { a0.x, a0.y, a0.z, a0.w,  a1.x, a1.y, a1.z, a1.w,
                     a2.x, a2.y, a2.z, a2.w,  a3.x, a3.y, a3.z, a3.w };
    dround_batch<16>(c1); dround_batch<16>(c1); dround_batch<16>(c1);
    float m1[4];
    filter_tail(c1, hb, vb, m1);

    // Deferred joint reduction: one 6-stage butterfly carrying 4 values.
    float im[4] = { i0, i1, i2, i3 };
    float sm0 = 0.f, si0 = 0.f, sm1 = 0.f, si1 = 0.f;
#pragma unroll
    for (int j = 0; j < 4; ++j) {
        sm0 += m0[j]; si0 += m0[j] * im[j];
        sm1 += m1[j]; si1 += m1[j] * im[j];
    }
#pragma unroll
    for (int off = 32; off; off >>= 1) {
        sm0 += __shfl_xor(sm0, off, 64);
        si0 += __shfl_xor(si0, off, 64);
        sm1 += __shfl_xor(sm1, off, 64);
        si1 += __shfl_xor(si1, off, 64);
    }

    // Guard 0/0: m >= 0 sums, so sm==0 implies every m==0 -> output 0.
    const float mean0 = (sm0 > 0.f) ? (si0 / sm0) : 0.f;
    const float mean1 = (sm1 > 0.f) ? (si1 / sm1) : 0.f;

    float* d0 = out     + base + lane;
    float* d1 = out_alt + base + lane;
#pragma unroll
    for (int k = 0; k < 4; ++k) {
        d0[64 * k] = m0[k] * mean0;   // 256B/instr, coalesced
        d1[64 * k] = m1[k] * mean1;
    }
}

extern "C" void kernel_launch(void* const* d_in, const int* in_sizes, int n_in,
                              void* d_out, int out_size, void* d_ws, size_t ws_size,
                              hipStream_t stream) {
    // setup_inputs() order (all float32 per reference):
    // 0: resized_image      [B,N,16,16,1]
    // 1: mask_combined      [B,N,16,16,4]
    // 2: mask_combined_alt  [B,N,16,16,4]
    // 3: initial_mask_id    [B,N,4]
    // 4: mask_new_bi_channel (unused)
    // 5: mask_index          (unused)
    const float* img      = (const float*)d_in[0];
    const float* mask     = (const float*)d_in[1];
    const float* mask_alt = (const float*)d_in[2];
    const float* mask_id  = (const float*)d_in[3];

    const int n_areas = out_size / 512;             // B*N = 16384
    float* out     = (float*)d_out;
    float* out_alt = out + (size_t)n_areas * 256;

    // One wave per area (handles both variants); 4 waves per 256-thread block.
    const int waves_per_block = 4;
    const int blocks = (n_areas + waves_per_block - 1) / waves_per_block;
    De_conv_areas_kernel<<<blocks, 256, 0, stream>>>(
        img, mask, mask_alt, mask_id, out, out_alt, n_areas);
}